// Round 1
// 99.191 us; speedup vs baseline: 1.0278x; 1.0278x over previous
//
#include <hip/hip_runtime.h>
#include <hip/hip_bf16.h>

// SubbandCompose R4: packed-fp32 (v_pk_fma_f32) DFT stage.
//
// y[t] = X[0] + (-1)^t X[64] + 2*sum_{m=1..63} X[m] cos(pi*m*t/64), t=0..64.
// With p = min(t,64-t):  E_p = sum_{even m} w_m X[m] cos(pi*m*p/64),
//                        O_p = sum_{odd  m} w_m X[m] cos(pi*m*p/64),
//   y[p] = E_p + O_p,  y[64-p] = E_p - O_p.
// out[s,i,j] = (1/512) * sum_{k=0..5} filt[k*64+j] * y[i+5-k][t(k,j)],
//   t(k,j) = j (k even);  (j==0 ? 64 : 64-j) (k odd).
//
// R4 change: stage-1 inner loop is float2-packed so the backend can emit
// v_pk_fma_f32 (2 FMAs/instr). The dwordx4 row load delivers the pairs
// {X[4c],X[4c+2]} / {X[4c+1],X[4c+3]} for free. Table row re-laid:
// [0..32]=even m (33), [33]=pad, [34..65]=odd m (32) so both pair streams
// are 8B-aligned for s_load_dwordx2.

#define NF 65
#define NT 8192
#define TRUE_LEN 8187
#define FPW 59              // output frames per wave (64 rows incl. 5 halo)
#define WPB 139             // waves per batch element: ceil(8187/59)
#define TAB_STRIDE 68       // table row stride (floats), 16B-aligned rows
#define YS_STRIDE 66        // bf16 elems per Ys row (64 rows per wave)

typedef const __attribute__((address_space(4))) float cfloat;
typedef float v2f __attribute__((ext_vector_type(2)));

__device__ float d_tab[33 * TAB_STRIDE];

__global__ void build_tab_kernel() {
    int idx = blockIdx.x * 256 + threadIdx.x;
    if (idx >= 33 * TAB_STRIDE) return;
    int p = idx / TAB_STRIDE, n = idx % TAB_STRIDE;
    // layout: [0..32] even m=2n; [33] pad; [34..65] odd m=2(n-34)+1; rest pad
    if (n == 33 || n >= 66) { d_tab[idx] = 0.0f; return; }
    int m = (n < 33) ? 2 * n : 2 * (n - 34) + 1;
    float w = (m == 0 || m == 64) ? 1.0f : 2.0f;
    int a = (m * p) & 127;                          // cos period 128
    d_tab[idx] = w * cospif((float)a * (1.0f / 64.0f));
}

__global__ __launch_bounds__(256)
void subband_main_kernel(const float* __restrict__ g_in,
                         const float* __restrict__ g_filt,
                         float* __restrict__ g_out)
{
    __shared__ __hip_bfloat16 Ys[4][64 * YS_STRIDE];  // wave-private regions

    const int tid  = threadIdx.x;
    const int lane = tid & 63;
    const int wv   = tid >> 6;
    const int wg   = blockIdx.x * 4 + wv;     // global wave id, 0..2223
    const int s     = wg / WPB;               // batch element
    const int fbase = (wg % WPB) * FPW;       // first output frame
    int h = fbase + lane;                     // this lane's spectrum row
    if (h > NT - 1) h = NT - 1;               // clamp (outputs using it are discarded)

    // ---- load this lane's 65-float spectrum row, packed even/odd pairs.
    // dwordx4 c covers X[4c..4c+3] = {even,odd,even,odd}:
    //   Xe[c] = {X[4c], X[4c+2]},  Xo[c] = {X[4c+1], X[4c+3]}
    const float* xr = g_in + ((size_t)s * NT + h) * NF;
    v2f Xe[17], Xo[16];
    #pragma unroll
    for (int c = 0; c < 16; ++c) {
        float t4[4];
        __builtin_memcpy(t4, xr + 4 * c, 16);
        Xe[c] = (v2f){t4[0], t4[2]};
        Xo[c] = (v2f){t4[1], t4[3]};
    }
    Xe[16] = (v2f){xr[64], 0.0f};             // pairs with {cf[32], pad}

    __hip_bfloat16* ys = &Ys[wv][0];
    cfloat* ct = (cfloat*)(unsigned long long)(const float*)d_tab;

    // ---- stage 1: p-loop; table streams via scalar pipe, packed FMAs
    for (int p = 0; p < 33; ++p) {
        cfloat* cf = ct + p * TAB_STRIDE;
        v2f aE = (v2f){0.0f, 0.0f}, aO = (v2f){0.0f, 0.0f};
        #pragma unroll
        for (int k = 0; k < 16; ++k) {
            v2f ce, co;
            __builtin_memcpy(&ce, cf + 2 * k, 8);        // {m=4k, m=4k+2}
            __builtin_memcpy(&co, cf + 34 + 2 * k, 8);   // {m=4k+1, m=4k+3}
            aE = __builtin_elementwise_fma(ce, Xe[k], aE);
            aO = __builtin_elementwise_fma(co, Xo[k], aO);
        }
        {   // edge: {cf[32]=w*cos(64p...), pad} * {X[64], 0}
            v2f ce;
            __builtin_memcpy(&ce, cf + 32, 8);
            aE = __builtin_elementwise_fma(ce, Xe[16], aE);
        }
        const float e = aE.x + aE.y, o = aO.x + aO.y;
        ys[lane * YS_STRIDE + p]      = __float2bfloat16(e + o);
        ys[lane * YS_STRIDE + 64 - p] = __float2bfloat16(e - o);
    }
    // wave-private LDS: DS pipe is in-order within a wave; no barrier needed.

    // ---- stage 2: 6-tap polyphase, rolling window, lane = j
    const int j = lane;
    float fc[6];
    #pragma unroll
    for (int k = 0; k < 6; ++k) fc[k] = g_filt[k * 64 + j] * (1.0f / 512.0f);
    const int te = j;
    const int to = (j == 0) ? 64 : 64 - j;

    float we[6], wo[6];
    #pragma unroll
    for (int r = 0; r < 5; ++r) {
        we[r] = __bfloat162float(ys[r * YS_STRIDE + te]);
        wo[r] = __bfloat162float(ys[r * YS_STRIDE + to]);
    }
    float* dst = g_out + ((size_t)s * TRUE_LEN + fbase) * 64 + j;

    #pragma unroll
    for (int q = 0; q < FPW; ++q) {
        if (fbase + q >= TRUE_LEN) break;
        we[5] = __bfloat162float(ys[(q + 5) * YS_STRIDE + te]);
        wo[5] = __bfloat162float(ys[(q + 5) * YS_STRIDE + to]);
        const float o = fc[0] * we[5] + fc[1] * wo[4] + fc[2] * we[3]
                      + fc[3] * wo[2] + fc[4] * we[1] + fc[5] * wo[0];
        dst[(size_t)q * 64] = o;
        #pragma unroll
        for (int r = 0; r < 5; ++r) { we[r] = we[r + 1]; wo[r] = wo[r + 1]; }
    }
}

extern "C" void kernel_launch(void* const* d_in, const int* in_sizes, int n_in,
                              void* d_out, int out_size, void* d_ws, size_t ws_size,
                              hipStream_t stream) {
    const float* g_in   = (const float*)d_in[0];  // (16,1,8192,65) fp32
    const float* g_filt = (const float*)d_in[1];  // (384,) fp32
    float* g_out = (float*)d_out;                 // (16,1,8187*64) fp32

    // table: 33*68 = 2244 entries
    build_tab_kernel<<<9, 256, 0, stream>>>();
    // 2224 waves = 556 blocks x 4 waves
    subband_main_kernel<<<556, 256, 0, stream>>>(g_in, g_filt, g_out);
}